// Round 1
// baseline (1252.911 us; speedup 1.0000x reference)
//
#include <hip/hip_runtime.h>
#include <math.h>

#define DEVINL __device__ __forceinline__

// Quadratic Cox-de Boor B-spline bases, exactly mirroring the reference:
// GRID_SIZE=3, SPLINE_ORDER=2, grid h=2/3, knots t_i=(i-2)*h-1, i=0..7.
DEVINL void bsplines5(float x, float bs[5]) {
    const float H3 = 2.0f / 3.0f;
    float g[8];
#pragma unroll
    for (int i = 0; i < 8; ++i) g[i] = (float)(i - 2) * H3 - 1.0f;
    float b0[7];
#pragma unroll
    for (int i = 0; i < 7; ++i) b0[i] = (x >= g[i] && x < g[i + 1]) ? 1.0f : 0.0f;
    float b1[6];
#pragma unroll
    for (int i = 0; i < 6; ++i) {
        float l = (x - g[i]) * (1.0f / (g[i + 1] - g[i]));
        float r = (g[i + 2] - x) * (1.0f / (g[i + 2] - g[i + 1]));
        b1[i] = l * b0[i] + r * b0[i + 1];
    }
#pragma unroll
    for (int i = 0; i < 5; ++i) {
        float l = (x - g[i]) * (1.0f / (g[i + 2] - g[i]));
        float r = (g[i + 3] - x) * (1.0f / (g[i + 3] - g[i + 1]));
        bs[i] = l * b1[i] + r * b1[i + 1];
    }
}

// Prep W6[k6][o], k6 = f*6 + s; s==0 -> base weight (pairs with relu(v)),
// s=1..5 -> spline_w * scaler (pairs with basis s-1).
__global__ void prep_w6(const float* __restrict__ bw, const float* __restrict__ sw,
                        const float* __restrict__ sc, float* __restrict__ w6,
                        int F, int COUT) {
    int idx = blockIdx.x * blockDim.x + threadIdx.x;
    if (idx >= F * 6 * COUT) return;
    int o = idx % COUT;
    int k6 = idx / COUT;
    int s = k6 % 6, f = k6 / 6;
    float v;
    if (s == 0) v = bw[o * F + f];
    else        v = sw[(o * F + f) * 5 + (s - 1)] * sc[o * F + f];
    w6[idx] = v;
}

// Fused KAN conv: im2col(4x4,s2,p1) + [relu | 5 spline bases] expansion + GEMM.
// Input NCHW fp32 (optionally BN-applied on read: v*bnscale[c]+bnshift[c],
// NOT applied to padding zeros), output NCHW fp32.
// Block: 256 threads, BM positions x COUT channels. K looped in chunks of one
// input channel (16 patch feats -> 96 expanded).
template <int CIN, int COUT, int HOUT, int WOUT, int BM, bool HASBN>
__global__ __launch_bounds__(256) void kan_conv_ker(
    const float* __restrict__ in, const float* __restrict__ w6,
    const float* __restrict__ bnscale, const float* __restrict__ bnshift,
    float* __restrict__ out) {
    constexpr int HIN = HOUT * 2, WIN = WOUT * 2;
    constexpr int KC = 96;               // expanded K per chunk (16 feats * 6)
    constexpr int ROWS = BM / 16;        // rows per thread
    constexpr int COLS = COUT / 16;      // cols per thread
    constexpr int SLOTS = BM * 16 / 256; // (pos,feat) pairs per thread per chunk

    __shared__ float EA[KC][BM];         // expanded A-tile, transposed [k][m]
    __shared__ float Wt[KC * COUT];      // weight tile [k][o]

    const int tid = threadIdx.x;
    const int m0 = blockIdx.x * BM;

    // Precompute per-slot gather geometry (only channel varies per chunk).
    int addr[SLOTS];
    int eoff[SLOTS];
    bool valid[SLOTS];
#pragma unroll
    for (int i2 = 0; i2 < SLOTS; ++i2) {
        int q = tid + 256 * i2;
        int p = q % BM;
        int fl = q / BM;                 // feature-in-chunk = kh*4+kw
        int m = m0 + p;
        int ow = m % WOUT;
        int t = m / WOUT;
        int oh = t % HOUT;
        int b = t / HOUT;
        int kh = fl >> 2, kw = fl & 3;
        int ih = oh * 2 - 1 + kh, iw = ow * 2 - 1 + kw;
        valid[i2] = ((unsigned)ih < (unsigned)HIN) && ((unsigned)iw < (unsigned)WIN);
        addr[i2] = (b * CIN * HIN + ih) * WIN + iw;  // + c*HIN*WIN per chunk
        eoff[i2] = fl * 6 * BM + p;
    }

    float acc[ROWS][COLS];
#pragma unroll
    for (int r = 0; r < ROWS; ++r)
#pragma unroll
        for (int c = 0; c < COLS; ++c) acc[r][c] = 0.0f;

    const int trow = tid >> 4, tcol = tid & 15;

    for (int ch = 0; ch < CIN; ++ch) {
        float bsc = 1.0f, bsh = 0.0f;
        if (HASBN) { bsc = bnscale[ch]; bsh = bnshift[ch]; }
        // Phase A: gather + expand into EA (writes conflict-free: lanes -> consecutive p)
#pragma unroll
        for (int i2 = 0; i2 < SLOTS; ++i2) {
            float v = 0.0f;
            if (valid[i2]) {
                v = in[addr[i2] + ch * (HIN * WIN)];
                if (HASBN) v = fmaf(v, bsc, bsh);  // padding zeros are NOT BN'd
            }
            float bs[5];
            bsplines5(v, bs);
            float* e = &EA[0][0] + eoff[i2];
            e[0 * BM] = fmaxf(v, 0.0f);
            e[1 * BM] = bs[0];
            e[2 * BM] = bs[1];
            e[3 * BM] = bs[2];
            e[4 * BM] = bs[3];
            e[5 * BM] = bs[4];
        }
        // Phase B: stage weight chunk (coalesced float4)
        {
            const float4* wsrc = (const float4*)(w6 + ch * (KC * COUT));
            float4* wdst = (float4*)Wt;
#pragma unroll
            for (int jj = 0; jj < KC * COUT / 4 / 256; ++jj)
                wdst[tid + jj * 256] = wsrc[tid + jj * 256];
        }
        __syncthreads();
        // Phase C: GEMM on the chunk
#pragma unroll 4
        for (int kc = 0; kc < KC; ++kc) {
            float e[ROWS];
#pragma unroll
            for (int r = 0; r < ROWS; ++r) e[r] = EA[kc][trow * ROWS + r];
            float w[COLS];
#pragma unroll
            for (int c = 0; c < COLS; ++c) w[c] = Wt[kc * COUT + tcol * COLS + c];
#pragma unroll
            for (int r = 0; r < ROWS; ++r)
#pragma unroll
                for (int c = 0; c < COLS; ++c) acc[r][c] = fmaf(e[r], w[c], acc[r][c]);
        }
        __syncthreads();
    }

    // Epilogue: NCHW store
#pragma unroll
    for (int r = 0; r < ROWS; ++r) {
        int p = trow * ROWS + r;
        int m = m0 + p;
        int ow = m % WOUT;
        int t = m / WOUT;
        int oh = t % HOUT;
        int b = t / HOUT;
#pragma unroll
        for (int c = 0; c < COLS; ++c) {
            int o = tcol * COLS + c;
            out[((b * COUT + o) * HOUT + oh) * WOUT + ow] = acc[r][c];
        }
    }
}

// Train-mode BN stats per channel -> fused scale/shift.
__global__ __launch_bounds__(256) void bn_stats(
    const float* __restrict__ a, const float* __restrict__ gamma,
    const float* __restrict__ beta, float* __restrict__ scale,
    float* __restrict__ shift, int C, int HW) {
    int c = blockIdx.x;
    int tid = threadIdx.x;
    int N = 512 * HW;
    float s = 0.0f, s2 = 0.0f;
    for (int i = tid; i < N; i += 256) {
        int b = i / HW, hw = i - (i / HW) * HW;
        float v = a[(b * C + c) * HW + hw];
        s += v;
        s2 += v * v;
    }
    __shared__ float red0[256], red1[256];
    red0[tid] = s; red1[tid] = s2;
    __syncthreads();
    for (int off = 128; off > 0; off >>= 1) {
        if (tid < off) { red0[tid] += red0[tid + off]; red1[tid] += red1[tid + off]; }
        __syncthreads();
    }
    if (tid == 0) {
        float mean = red0[0] / (float)N;
        float var = red1[0] / (float)N - mean * mean;
        float rs = rsqrtf(var + 1e-5f);
        float scl = gamma[c] * rs;
        scale[c] = scl;
        shift[c] = beta[c] - mean * scl;
    }
}

// BN3 + avgpool(2x2) + FC(128->1) + sigmoid. One wave per batch element.
__global__ void head_ker(const float* __restrict__ a4, const float* __restrict__ scale,
                         const float* __restrict__ shift, const float* __restrict__ fcw,
                         const float* __restrict__ fcb, float* __restrict__ out) {
    int b = blockIdx.x;
    int lane = threadIdx.x;  // 64
    float acc = 0.0f;
#pragma unroll
    for (int j = 0; j < 2; ++j) {
        int o = lane + 64 * j;
        const float* p = a4 + (b * 128 + o) * 4;
        float sv = p[0] + p[1] + p[2] + p[3];
        float pooled = fmaf(sv * 0.25f, scale[o], shift[o]);
        acc = fmaf(pooled, fcw[o], acc);
    }
#pragma unroll
    for (int off = 32; off > 0; off >>= 1) acc += __shfl_down(acc, off);
    if (lane == 0) out[b] = 1.0f / (1.0f + expf(-(acc + fcb[0])));
}

extern "C" void kernel_launch(void* const* d_in, const int* in_sizes, int n_in,
                              void* d_out, int out_size, void* d_ws, size_t ws_size,
                              hipStream_t stream) {
    const float* x   = (const float*)d_in[0];
    const float* bw1 = (const float*)d_in[1];
    const float* sw1 = (const float*)d_in[2];
    const float* sc1 = (const float*)d_in[3];
    const float* bw2 = (const float*)d_in[4];
    const float* sw2 = (const float*)d_in[5];
    const float* sc2 = (const float*)d_in[6];
    const float* bw3 = (const float*)d_in[7];
    const float* sw3 = (const float*)d_in[8];
    const float* sc3 = (const float*)d_in[9];
    const float* bw4 = (const float*)d_in[10];
    const float* sw4 = (const float*)d_in[11];
    const float* sc4 = (const float*)d_in[12];
    const float* g1  = (const float*)d_in[13];
    const float* b1  = (const float*)d_in[14];
    const float* g2  = (const float*)d_in[15];
    const float* b2  = (const float*)d_in[16];
    const float* g3  = (const float*)d_in[17];
    const float* b3  = (const float*)d_in[18];
    const float* fcw = (const float*)d_in[19];
    const float* fcb = (const float*)d_in[20];

    float* ws = (float*)d_ws;
    float* a1 = ws;                    // 512*32*16*16 = 4194304
    float* a2 = a1 + 4194304;          // 512*64*8*8   = 2097152
    float* a3 = a2 + 2097152;          // 512*128*4*4  = 1048576
    float* a4 = a3 + 1048576;          // 512*128*2*2  = 262144
    float* w61 = a4 + 262144;          // 288*32    = 9216
    float* w62 = w61 + 9216;           // 3072*64   = 196608
    float* w63 = w62 + 196608;         // 6144*128  = 786432
    float* w64 = w63 + 786432;         // 12288*128 = 1572864
    float* bnsc1 = w64 + 1572864;      // 64
    float* bnsh1 = bnsc1 + 64;
    float* bnsc2 = bnsh1 + 64;         // 128
    float* bnsh2 = bnsc2 + 128;
    float* bnsc3 = bnsh2 + 128;        // 128
    float* bnsh3 = bnsc3 + 128;

    prep_w6<<<(288 * 32 + 255) / 256, 256, 0, stream>>>(bw1, sw1, sc1, w61, 48, 32);
    prep_w6<<<(3072 * 64 + 255) / 256, 256, 0, stream>>>(bw2, sw2, sc2, w62, 512, 64);
    prep_w6<<<(6144 * 128 + 255) / 256, 256, 0, stream>>>(bw3, sw3, sc3, w63, 1024, 128);
    prep_w6<<<(12288 * 128 + 255) / 256, 256, 0, stream>>>(bw4, sw4, sc4, w64, 2048, 128);

    // L1: (512,3,32,32) -> (512,32,16,16), M=131072
    kan_conv_ker<3, 32, 16, 16, 64, false><<<2048, 256, 0, stream>>>(x, w61, nullptr, nullptr, a1);
    // L2: -> (512,64,8,8), M=32768
    kan_conv_ker<32, 64, 8, 8, 64, false><<<512, 256, 0, stream>>>(a1, w62, nullptr, nullptr, a2);
    bn_stats<<<64, 256, 0, stream>>>(a2, g1, b1, bnsc1, bnsh1, 64, 64);
    // L3: -> (512,128,4,4), M=8192 (BN1 folded into gather)
    kan_conv_ker<64, 128, 4, 4, 32, true><<<256, 256, 0, stream>>>(a2, w63, bnsc1, bnsh1, a3);
    bn_stats<<<128, 256, 0, stream>>>(a3, g2, b2, bnsc2, bnsh2, 128, 16);
    // L4: -> (512,128,2,2), M=2048 (BN2 folded)
    kan_conv_ker<128, 128, 2, 2, 16, true><<<128, 256, 0, stream>>>(a3, w64, bnsc2, bnsh2, a4);
    bn_stats<<<128, 256, 0, stream>>>(a4, g3, b3, bnsc3, bnsh3, 128, 4);
    // Head: BN3 + pool + FC + sigmoid
    head_ker<<<512, 64, 0, stream>>>(a4, bnsc3, bnsh3, fcw, fcb, (float*)d_out);
}

// Round 2
// 290.105 us; speedup vs baseline: 4.3188x; 4.3188x over previous
//
#include <hip/hip_runtime.h>
#include <math.h>

#define DEVINL __device__ __forceinline__

typedef short short8 __attribute__((ext_vector_type(8)));
typedef float f32x4 __attribute__((ext_vector_type(4)));

DEVINL unsigned short f2bf(float f) {
    union { float f; unsigned int u; } c; c.f = f;
    unsigned int u = c.u;
    return (unsigned short)((u + 0x7fffu + ((u >> 16) & 1u)) >> 16);
}
DEVINL unsigned int packbf(float a, float b) {
    return (unsigned int)f2bf(a) | ((unsigned int)f2bf(b) << 16);
}

DEVINL void gload_lds16(const unsigned int* g, unsigned int* l) {
    __builtin_amdgcn_global_load_lds((const __attribute__((address_space(1))) unsigned int*)g,
                                     (__attribute__((address_space(3))) unsigned int*)l, 16, 0, 0);
}

// Quadratic Cox-de Boor B-spline bases (GRID_SIZE=3, SPLINE_ORDER=2).
DEVINL void bsplines5(float x, float bs[5]) {
    const float H3 = 2.0f / 3.0f;
    float g[8];
#pragma unroll
    for (int i = 0; i < 8; ++i) g[i] = (float)(i - 2) * H3 - 1.0f;
    float b0[7];
#pragma unroll
    for (int i = 0; i < 7; ++i) b0[i] = (x >= g[i] && x < g[i + 1]) ? 1.0f : 0.0f;
    float b1[6];
#pragma unroll
    for (int i = 0; i < 6; ++i) {
        float l = (x - g[i]) * (1.0f / (g[i + 1] - g[i]));
        float r = (g[i + 2] - x) * (1.0f / (g[i + 2] - g[i + 1]));
        b1[i] = l * b0[i] + r * b0[i + 1];
    }
#pragma unroll
    for (int i = 0; i < 5; ++i) {
        float l = (x - g[i]) * (1.0f / (g[i + 2] - g[i]));
        float r = (g[i + 3] - x) * (1.0f / (g[i + 3] - g[i + 1]));
        bs[i] = l * b1[i] + r * b1[i + 1];
    }
}

// Pack weights into MFMA B-fragment-linear layout (bf16):
// wf[(((c*NT + nt)*3 + ks)*64 + lane)*8 + j] = W6[c*96 + k][o]
// with k = ks*32 + (lane>>4)*8 + j, o = nt*16 + (lane&15).
// W6 row k6 = f*6+s: s==0 -> bw (pairs with relu), s>=1 -> sw*sc (basis s-1).
template <int CIN, int COUT>
__global__ __launch_bounds__(256) void prep_wfrag(const float* __restrict__ bw,
                                                  const float* __restrict__ sw,
                                                  const float* __restrict__ sc,
                                                  unsigned short* __restrict__ wf) {
    constexpr int F = CIN * 16;
    constexpr int NT = COUT / 16;
    int idx = blockIdx.x * 256 + threadIdx.x;
    if (idx >= CIN * 96 * COUT) return;
    int j = idx & 7;
    int lane = (idx >> 3) & 63;
    int t = idx >> 9;        // (c*NT + nt)*3 + ks
    int ks = t % 3;
    int t2 = t / 3;
    int nt = t2 % NT;
    int c = t2 / NT;
    int k = ks * 32 + ((lane >> 4) << 3) + j;
    int o = nt * 16 + (lane & 15);
    int f = c * 16 + k / 6;
    int s = k % 6;
    float v = (s == 0) ? bw[o * F + f] : sw[(o * F + f) * 5 + (s - 1)] * sc[o * F + f];
    wf[idx] = f2bf(v);
}

// Fused KAN conv via MFMA. Gathers fp32 NCHW input (optional folded BN,
// not applied to padding), expands [relu | 5 bases], scatters bf16 pairs into
// A-fragment-linear LDS, stages fragment-linear weights via global_load_lds,
// runs mfma_f32_16x16x32_bf16, accumulates fp32.
// Grid: (M/BM, SPLIT). Each y-slice handles CPS input channels.
template <int CIN, int COUT, int HOUT, int WOUT, int BM, int CPS, bool HASBN, bool SPLITOUT>
__global__ __launch_bounds__(256) void kan_conv_mfma(
    const float* __restrict__ in, const unsigned short* __restrict__ wf,
    const float* __restrict__ bnscale, const float* __restrict__ bnshift,
    float* __restrict__ out) {
    constexpr int HIN = HOUT * 2, WIN = WOUT * 2;
    constexpr int NT = COUT / 16;
    constexpr int MT = BM / 16;
    constexpr int SLOTS = BM / 16;            // evals per thread per chunk
    constexpr int WM = (MT >= 4) ? 4 : MT;    // waves along M
    constexpr int WN = 4 / WM;                // waves along N
    constexpr int NTW = NT / WN;              // n-tiles per wave
    constexpr int ABYTES = MT * 3 * 64 * 16;  // = BM*192
    constexpr int BBYTES = NT * 3 * 64 * 16;  // = COUT*192
    constexpr int M_TOT = 512 * HOUT * WOUT;

    __shared__ unsigned short A_us[ABYTES / 2];
    __shared__ unsigned short B_us[BBYTES / 2];

    const int tid = threadIdx.x;
    const int lane = tid & 63;
    const int w = tid >> 6;
    const int m0 = blockIdx.x * BM;
    const int slice = SPLITOUT ? blockIdx.y : 0;
    const int c0 = slice * CPS;

    // Per-slot gather geometry + A-scatter word offsets (channel-invariant).
    int addr[SLOTS];
    bool valid[SLOTS];
    int woff[SLOTS][3];
#pragma unroll
    for (int i = 0; i < SLOTS; ++i) {
        int q = tid + 256 * i;
        int fl = q & 15;                 // patch tap kh*4+kw
        int p = q >> 4;                  // position within BM
        int m = m0 + p;
        int ow = m % WOUT;
        int t = m / WOUT;
        int oh = t % HOUT;
        int b = t / HOUT;
        int kh = fl >> 2, kw = fl & 3;
        int ih = oh * 2 - 1 + kh, iw = ow * 2 - 1 + kw;
        valid[i] = ((unsigned)ih < (unsigned)HIN) && ((unsigned)iw < (unsigned)WIN);
        addr[i] = ((b * CIN) * HIN + ih) * WIN + iw;
        int mt = p >> 4, r = p & 15;
#pragma unroll
        for (int tt = 0; tt < 3; ++tt) {
            int k = fl * 6 + tt * 2;
            int ks = k >> 5, kr = k & 31, kb = kr >> 3, jj = kr & 7;
            woff[i][tt] = ((mt * 3 + ks) * 64 + (r | (kb << 4))) * 4 + (jj >> 1);
        }
    }

    f32x4 acc[NTW];
    const f32x4 zero = {0.f, 0.f, 0.f, 0.f};
#pragma unroll
    for (int n = 0; n < NTW; ++n) acc[n] = zero;

    const int mt_w = w % WM;
    const int wn = w / WM;
    const int noff = wn * NTW;

    for (int cc = 0; cc < CPS; ++cc) {
        const int ch = c0 + cc;
        // (1) issue B staging (fragment-linear contiguous copy, overlaps (2))
        {
            const unsigned int* bsrc = (const unsigned int*)(wf + (size_t)ch * (NT * 1536));
            unsigned int* bdst = (unsigned int*)B_us;
            constexpr int ROUNDS = BBYTES / 4096;
            constexpr int REM = (BBYTES % 4096) / 16;
#pragma unroll
            for (int r2 = 0; r2 < ROUNDS; ++r2)
                gload_lds16(bsrc + (r2 * 256 + tid) * 4, bdst + (r2 * 256 + tid) * 4);
            if constexpr (REM > 0) {
                if (tid < REM)
                    gload_lds16(bsrc + (ROUNDS * 256 + tid) * 4, bdst + (ROUNDS * 256 + tid) * 4);
            }
        }
        // (2) gather + expand + scatter into A (fragment-linear)
        float bsc = 1.f, bsh = 0.f;
        if (HASBN) { bsc = bnscale[ch]; bsh = bnshift[ch]; }
        unsigned int* Aw = (unsigned int*)A_us;
#pragma unroll
        for (int i = 0; i < SLOTS; ++i) {
            float v = 0.f;
            if (valid[i]) {
                v = in[addr[i] + ch * (HIN * WIN)];
                if (HASBN) v = fmaf(v, bsc, bsh);  // padding zeros NOT BN'd
            }
            float e0 = fmaxf(v, 0.f);
            float bs[5];
            bsplines5(v, bs);
            Aw[woff[i][0]] = packbf(e0, bs[0]);
            Aw[woff[i][1]] = packbf(bs[1], bs[2]);
            Aw[woff[i][2]] = packbf(bs[3], bs[4]);
        }
        __syncthreads();  // drains vmcnt (B staged) + lgkm (A visible)
        // (3) MFMA: 3 k-steps x NTW n-tiles
#pragma unroll
        for (int ks = 0; ks < 3; ++ks) {
            short8 af = *(const short8*)&A_us[((mt_w * 3 + ks) << 9) + (lane << 3)];
#pragma unroll
            for (int n = 0; n < NTW; ++n) {
                short8 bf = *(const short8*)&B_us[(((noff + n) * 3 + ks) << 9) + (lane << 3)];
                acc[n] = __builtin_amdgcn_mfma_f32_16x16x32_bf16(af, bf, acc[n], 0, 0, 0);
            }
        }
        __syncthreads();
    }

    // Epilogue. D mapping: col=lane&15, row=(lane>>4)*4+reg [m89].
    const int colo = lane & 15;
    const int row4 = (lane >> 4) * 4;
#pragma unroll
    for (int n = 0; n < NTW; ++n) {
        int o = (noff + n) * 16 + colo;
#pragma unroll
        for (int r = 0; r < 4; ++r) {
            int p = mt_w * 16 + row4 + r;
            int m = m0 + p;
            if (SPLITOUT) {
                out[(size_t)slice * M_TOT * COUT + (size_t)m * COUT + o] = acc[n][r];
            } else {
                int ow = m % WOUT;
                int t = m / WOUT;
                int oh = t % HOUT;
                int b = t / HOUT;
                out[((b * COUT + o) * HOUT + oh) * WOUT + ow] = acc[n][r];
            }
        }
    }
}

// Deterministic fixed-order reduction of split-K partials -> NCHW.
template <int NS, int COUT, int HOUT, int WOUT>
__global__ __launch_bounds__(256) void reduce_split(const float* __restrict__ P,
                                                    float* __restrict__ out) {
    constexpr int M = 512 * HOUT * WOUT;
    int idx = blockIdx.x * 256 + threadIdx.x;
    if (idx >= M * COUT) return;
    float s = 0.f;
#pragma unroll
    for (int i = 0; i < NS; ++i) s += P[(size_t)i * M * COUT + idx];
    int o = idx % COUT;
    int m = idx / COUT;
    int ow = m % WOUT;
    int t = m / WOUT;
    int oh = t % HOUT;
    int b = t / HOUT;
    out[((b * COUT + o) * HOUT + oh) * WOUT + ow] = s;
}

// Train-mode BN stats per channel -> fused scale/shift.
__global__ __launch_bounds__(256) void bn_stats(
    const float* __restrict__ a, const float* __restrict__ gamma,
    const float* __restrict__ beta, float* __restrict__ scale,
    float* __restrict__ shift, int C, int HW) {
    int c = blockIdx.x;
    int tid = threadIdx.x;
    int N = 512 * HW;
    float s = 0.0f, s2 = 0.0f;
    for (int i = tid; i < N; i += 256) {
        int b = i / HW, hw = i - (i / HW) * HW;
        float v = a[(b * C + c) * HW + hw];
        s += v;
        s2 += v * v;
    }
    __shared__ float red0[256], red1[256];
    red0[tid] = s; red1[tid] = s2;
    __syncthreads();
    for (int off = 128; off > 0; off >>= 1) {
        if (tid < off) { red0[tid] += red0[tid + off]; red1[tid] += red1[tid + off]; }
        __syncthreads();
    }
    if (tid == 0) {
        float mean = red0[0] / (float)N;
        float var = red1[0] / (float)N - mean * mean;
        float rs = rsqrtf(var + 1e-5f);
        float scl = gamma[c] * rs;
        scale[c] = scl;
        shift[c] = beta[c] - mean * scl;
    }
}

// BN3 + avgpool(2x2) + FC(128->1) + sigmoid. One wave per batch element.
__global__ void head_ker(const float* __restrict__ a4, const float* __restrict__ scale,
                         const float* __restrict__ shift, const float* __restrict__ fcw,
                         const float* __restrict__ fcb, float* __restrict__ out) {
    int b = blockIdx.x;
    int lane = threadIdx.x;  // 64
    float acc = 0.0f;
#pragma unroll
    for (int j = 0; j < 2; ++j) {
        int o = lane + 64 * j;
        const float* p = a4 + (b * 128 + o) * 4;
        float sv = p[0] + p[1] + p[2] + p[3];
        float pooled = fmaf(sv * 0.25f, scale[o], shift[o]);
        acc = fmaf(pooled, fcw[o], acc);
    }
#pragma unroll
    for (int off = 32; off > 0; off >>= 1) acc += __shfl_down(acc, off);
    if (lane == 0) out[b] = 1.0f / (1.0f + expf(-(acc + fcb[0])));
}

extern "C" void kernel_launch(void* const* d_in, const int* in_sizes, int n_in,
                              void* d_out, int out_size, void* d_ws, size_t ws_size,
                              hipStream_t stream) {
    const float* x   = (const float*)d_in[0];
    const float* bw1 = (const float*)d_in[1];
    const float* sw1 = (const float*)d_in[2];
    const float* sc1 = (const float*)d_in[3];
    const float* bw2 = (const float*)d_in[4];
    const float* sw2 = (const float*)d_in[5];
    const float* sc2 = (const float*)d_in[6];
    const float* bw3 = (const float*)d_in[7];
    const float* sw3 = (const float*)d_in[8];
    const float* sc3 = (const float*)d_in[9];
    const float* bw4 = (const float*)d_in[10];
    const float* sw4 = (const float*)d_in[11];
    const float* sc4 = (const float*)d_in[12];
    const float* g1  = (const float*)d_in[13];
    const float* b1  = (const float*)d_in[14];
    const float* g2  = (const float*)d_in[15];
    const float* b2  = (const float*)d_in[16];
    const float* g3  = (const float*)d_in[17];
    const float* b3  = (const float*)d_in[18];
    const float* fcw = (const float*)d_in[19];
    const float* fcb = (const float*)d_in[20];

    float* ws = (float*)d_ws;
    float* a1 = ws;                    // 4194304 floats (dead after L2 -> reused as P3)
    float* a2 = a1 + 4194304;          // 2097152 (dead after L3 -> reused as P4)
    float* a3 = a2 + 2097152;          // 1048576
    float* a4 = a3 + 1048576;          // 262144
    float* bnsc1 = a4 + 262144;        // 64
    float* bnsh1 = bnsc1 + 64;
    float* bnsc2 = bnsh1 + 64;         // 128
    float* bnsh2 = bnsc2 + 128;
    float* bnsc3 = bnsh2 + 128;        // 128
    float* bnsh3 = bnsc3 + 128;        // +128
    unsigned short* wf1 = (unsigned short*)(bnsh3 + 128);  // 9216 ushorts
    unsigned short* wf2 = wf1 + 9216;       // 196608
    unsigned short* wf3 = wf2 + 196608;     // 786432
    unsigned short* wf4 = wf3 + 786432;     // 1572864
    float* P3 = a1;                    // 4 * 8192*128 = 4194304 floats
    float* P4 = a2;                    // 8 * 2048*128 = 2097152 floats

    prep_wfrag<3, 32><<<36, 256, 0, stream>>>(bw1, sw1, sc1, wf1);
    prep_wfrag<32, 64><<<768, 256, 0, stream>>>(bw2, sw2, sc2, wf2);
    prep_wfrag<64, 128><<<3072, 256, 0, stream>>>(bw3, sw3, sc3, wf3);
    prep_wfrag<128, 128><<<6144, 256, 0, stream>>>(bw4, sw4, sc4, wf4);

    // L1: (512,3,32,32) -> (512,32,16,16), M=131072
    kan_conv_mfma<3, 32, 16, 16, 64, 3, false, false>
        <<<2048, 256, 0, stream>>>(x, wf1, nullptr, nullptr, a1);
    // L2: -> (512,64,8,8), M=32768
    kan_conv_mfma<32, 64, 8, 8, 64, 32, false, false>
        <<<512, 256, 0, stream>>>(a1, wf2, nullptr, nullptr, a2);
    bn_stats<<<64, 256, 0, stream>>>(a2, g1, b1, bnsc1, bnsh1, 64, 64);
    // L3: -> (512,128,4,4), M=8192; split-K 4 x 16ch, BN1 folded
    kan_conv_mfma<64, 128, 4, 4, 64, 16, true, true>
        <<<dim3(128, 4), 256, 0, stream>>>(a2, wf3, bnsc1, bnsh1, P3);
    reduce_split<4, 128, 4, 4><<<4096, 256, 0, stream>>>(P3, a3);
    bn_stats<<<128, 256, 0, stream>>>(a3, g2, b2, bnsc2, bnsh2, 128, 16);
    // L4: -> (512,128,2,2), M=2048; split-K 8 x 16ch, BN2 folded
    kan_conv_mfma<128, 128, 2, 2, 32, 16, true, true>
        <<<dim3(64, 8), 256, 0, stream>>>(a3, wf4, bnsc2, bnsh2, P4);
    reduce_split<8, 128, 2, 2><<<1024, 256, 0, stream>>>(P4, a4);
    bn_stats<<<128, 256, 0, stream>>>(a4, g3, b3, bnsc3, bnsh3, 128, 4);
    // Head: BN3 + pool + FC + sigmoid
    head_ker<<<512, 64, 0, stream>>>(a4, bnsc3, bnsh3, fcw, fcb, (float*)d_out);
}

// Round 3
// 209.792 us; speedup vs baseline: 5.9721x; 1.3828x over previous
//
#include <hip/hip_runtime.h>
#include <hip/hip_bf16.h>
#include <math.h>

#define DEVINL __device__ __forceinline__

typedef short short8 __attribute__((ext_vector_type(8)));
typedef float f32x4 __attribute__((ext_vector_type(4)));

DEVINL unsigned short f2bf(float f) {
    union { float f; unsigned int u; } c; c.f = f;
    unsigned int u = c.u;
    return (unsigned short)((u + 0x7fffu + ((u >> 16) & 1u)) >> 16);
}

DEVINL unsigned int packbf2(float a, float b) {
    union { __hip_bfloat162 h; unsigned int u; } c;
    c.h = __float22bfloat162_rn(make_float2(a, b));
    return c.u;  // a in low 16, b in high 16
}

DEVINL void gload_lds16(const unsigned int* g, unsigned int* l) {
    __builtin_amdgcn_global_load_lds((const __attribute__((address_space(1))) unsigned int*)g,
                                     (__attribute__((address_space(3))) unsigned int*)l, 16, 0, 0);
}

// Closed-form quadratic B-spline expansion on the uniform extended grid
// (knots t_i=(i-2)*(2/3)-1): u = (x-t0)/h = 1.5x+3.5, j=floor(u), t=u-j.
// Nonzero bases: B[j-2]=(1-t)^2/2, B[j-1]=1/2+t(1-t), B[j]=t^2/2 (if in [0,5)).
// Frag = bf16x8 [relu(x), b0..b4, 0, 0].
DEVINL uint4 expand_frag(float v) {
    float relu = fmaxf(v, 0.f);
    float u = fmaf(v, 1.5f, 3.5f);
    float fj = floorf(u);
    int j = (int)fj;
    float t = u - fj;
    float omt = 1.f - t;
    float v2 = 0.5f * omt * omt;
    float v1 = fmaf(t, omt, 0.5f);
    float v0 = 0.5f * t * t;
    float b[5];
#pragma unroll
    for (int i = 0; i < 5; ++i)
        b[i] = (i == j) ? v0 : (i == j - 1) ? v1 : (i == j - 2) ? v2 : 0.f;
    uint4 r;
    r.x = packbf2(relu, b[0]);
    r.y = packbf2(b[1], b[2]);
    r.z = packbf2(b[3], b[4]);
    r.w = 0u;
    return r;
}

// Pack weights into MFMA B-fragment-linear layout, K padded to 8 slots/tap:
// wf[(((c*NT+nt)*4+ks)*64+lane)*8+j] = W[k][o], k=ks*32+(lane>>4)*8+j,
// o=nt*16+(lane&15); tap=k>>3 (=kh*4+kw), s=k&7: s==0->bw, 1..5->sw*sc, 6,7->0.
template <int CIN, int COUT>
__global__ __launch_bounds__(256) void prep_wfrag(const float* __restrict__ bw,
                                                  const float* __restrict__ sw,
                                                  const float* __restrict__ sc,
                                                  unsigned short* __restrict__ wf) {
    constexpr int F = CIN * 16;
    constexpr int NT = COUT / 16;
    int idx = blockIdx.x * 256 + threadIdx.x;
    if (idx >= CIN * COUT * 128) return;
    int j = idx & 7;
    int lane = (idx >> 3) & 63;
    int t = idx >> 9;        // (c*NT+nt)*4 + ks
    int ks = t & 3;
    int t2 = t >> 2;
    int nt = t2 % NT;
    int c = t2 / NT;
    int k = ks * 32 + ((lane >> 4) << 3) + j;
    int tap = k >> 3, s = k & 7;
    int f = c * 16 + tap;
    int o = nt * 16 + (lane & 15);
    float v = 0.f;
    if (s == 0) v = bw[o * F + f];
    else if (s <= 5) v = sw[(o * F + f) * 5 + (s - 1)] * sc[o * F + f];
    wf[idx] = f2bf(v);
}

// Fused KAN conv: per channel {stage B (global_load_lds, fragment-linear) ||
// expand input tile once into parity-split LDS} -> barrier -> MFMA -> barrier.
// 4 waves (WM x WN), per-wave tile MT x NTW 16x16 frags, K=128/channel.
// Invalid (padding) taps read LDS slot 0 = expansion of v=0 (not BN'd).
template <int CIN, int COUT, int HOUT, int WOUT, int WM, int WN, int MT, int CPS,
          bool HASBN, bool SPLITOUT, int RPAD>
__global__ __launch_bounds__(256) void kan_conv_fused(
    const float* __restrict__ in, const unsigned short* __restrict__ wf,
    const float* __restrict__ bnscale, const float* __restrict__ bnshift,
    float* __restrict__ out) {
    constexpr int HIN = HOUT * 2, WIN = WOUT * 2, W2 = WOUT;
    constexpr int NT = COUT / 16;
    constexpr int NTW = NT / WN;
    constexpr int BM = WM * MT * 16;
    constexpr int IMG_POS = HOUT * WOUT;
    constexpr int NIMG = BM / IMG_POS;
    constexpr int RS = WIN + RPAD;                 // LDS row stride (slots)
    constexpr int IMG_STRIDE = HIN * RS + 1;       // +1: inter-image bank shift
    constexpr int ASLOTS = NIMG * IMG_STRIDE + 1;  // slot 0 = pad frag
    constexpr int M_TOT = 512 * IMG_POS;
    constexpr int EV = NIMG * HIN * WIN;
    constexpr int EITER = (EV + 255) / 256;
    static_assert(WM * WN == 4, "4 waves");

    __shared__ uint4 A_e[ASLOTS];
    __shared__ uint4 B_l[COUT * 16];

    const int tid = threadIdx.x;
    const int lane = tid & 63;
    const int w = tid >> 6;
    const int wm = w % WM;
    const int wn = w / WM;
    const int g = lane >> 4;        // kw
    const int r16 = lane & 15;
    const int m0 = blockIdx.x * BM;
    const int b0 = m0 / IMG_POS;
    const int c0 = SPLITOUT ? blockIdx.y * CPS : 0;

    // Per-mt fragment geometry (channel-invariant).
    int aoff[MT];
    int vmask = 0;
#pragma unroll
    for (int mt = 0; mt < MT; ++mt) {
        int p = (wm * MT + mt) * 16 + r16;
        int m = m0 + p;
        int ow = m % WOUT;
        int oh = (m / WOUT) % HOUT;
        int bl = p / IMG_POS;
        int iw = 2 * ow - 1 + g;
        bool iv = (iw >= 0) && (iw < WIN);
        aoff[mt] = 1 + bl * IMG_STRIDE + (2 * oh) * RS + (iw & 1) * W2 + (iw >> 1);
#pragma unroll
        for (int ks = 0; ks < 4; ++ks) {
            bool vv = iv && !(oh == 0 && ks == 0) && !(oh == HOUT - 1 && ks == 3);
            vmask |= (vv ? 1 : 0) << (mt * 4 + ks);
        }
    }

    if (tid == 0) A_e[0] = expand_frag(0.f);  // pad slot (covered by 1st barrier)

    f32x4 acc[MT][NTW];
#pragma unroll
    for (int mt = 0; mt < MT; ++mt)
#pragma unroll
        for (int n = 0; n < NTW; ++n) acc[mt][n] = f32x4{0.f, 0.f, 0.f, 0.f};

    for (int cc = 0; cc < CPS; ++cc) {
        const int ch = c0 + cc;
        // (1) async-stage B fragments (contiguous per channel)
        {
            const unsigned int* bsrc = (const unsigned int*)(wf + (size_t)ch * (COUT * 128));
            unsigned int* bdst = (unsigned int*)B_l;
#pragma unroll
            for (int r2 = 0; r2 < NT; ++r2)
                gload_lds16(bsrc + ((r2 << 8) + tid) * 4, bdst + ((r2 << 8) + tid) * 4);
        }
        // (2) expand this channel's input tile into LDS (once per element)
        float bsc = 1.f, bsh = 0.f;
        if (HASBN) { bsc = bnscale[ch]; bsh = bnshift[ch]; }
#pragma unroll
        for (int ii = 0; ii < EITER; ++ii) {
            int e = tid + ii * 256;
            if (e < EV) {
                int bl = e / (HIN * WIN);
                int r = e - bl * (HIN * WIN);
                int ih = r / WIN;
                int iw = r - ih * WIN;
                float v = in[(((size_t)(b0 + bl) * CIN + ch) * HIN + ih) * WIN + iw];
                if (HASBN) v = fmaf(v, bsc, bsh);
                A_e[1 + bl * IMG_STRIDE + ih * RS + (iw & 1) * W2 + (iw >> 1)] = expand_frag(v);
            }
        }
        __syncthreads();  // drains gload_lds (vmcnt) + ds_writes (lgkm)
        // (3) MFMA: 4 k-steps (kh) x MT x NTW
#pragma unroll
        for (int ks = 0; ks < 4; ++ks) {
            short8 bf[NTW];
#pragma unroll
            for (int n = 0; n < NTW; ++n)
                bf[n] = *(const short8*)&B_l[(((wn * NTW + n) * 4 + ks) << 6) + lane];
#pragma unroll
            for (int mt = 0; mt < MT; ++mt) {
                int slot = ((vmask >> (mt * 4 + ks)) & 1) ? (aoff[mt] + (ks - 1) * RS) : 0;
                short8 af = *(const short8*)&A_e[slot];
#pragma unroll
                for (int n = 0; n < NTW; ++n)
                    acc[mt][n] = __builtin_amdgcn_mfma_f32_16x16x32_bf16(af, bf[n], acc[mt][n], 0, 0, 0);
            }
        }
        __syncthreads();  // A_e/B_l reused next channel
    }

    // Epilogue. D mapping: col=lane&15, row=(lane>>4)*4+reg [m89].
    const int colo = lane & 15;
    const int row4 = (lane >> 4) * 4;
#pragma unroll
    for (int mt = 0; mt < MT; ++mt) {
#pragma unroll
        for (int n = 0; n < NTW; ++n) {
            int o = (wn * NTW + n) * 16 + colo;
#pragma unroll
            for (int rr = 0; rr < 4; ++rr) {
                int p = (wm * MT + mt) * 16 + row4 + rr;
                int m = m0 + p;
                if (SPLITOUT) {
                    out[((size_t)blockIdx.y * M_TOT + m) * COUT + o] = acc[mt][n][rr];
                } else {
                    int ow = m % WOUT;
                    int t = m / WOUT;
                    int oh = t % HOUT;
                    int b = t / HOUT;
                    out[((b * COUT + o) * HOUT + oh) * WOUT + ow] = acc[mt][n][rr];
                }
            }
        }
    }
}

// Deterministic fixed-order reduction of split-K partials -> NCHW.
template <int NS, int COUT, int HOUT, int WOUT>
__global__ __launch_bounds__(256) void reduce_split(const float* __restrict__ P,
                                                    float* __restrict__ out) {
    constexpr int M = 512 * HOUT * WOUT;
    int idx = blockIdx.x * 256 + threadIdx.x;
    if (idx >= M * COUT) return;
    float s = 0.f;
#pragma unroll
    for (int i = 0; i < NS; ++i) s += P[(size_t)i * M * COUT + idx];
    int o = idx % COUT;
    int m = idx / COUT;
    int ow = m % WOUT;
    int t = m / WOUT;
    int oh = t % HOUT;
    int b = t / HOUT;
    out[((b * COUT + o) * HOUT + oh) * WOUT + ow] = s;
}

// Train-mode BN stats per channel -> fused scale/shift.
__global__ __launch_bounds__(256) void bn_stats(
    const float* __restrict__ a, const float* __restrict__ gamma,
    const float* __restrict__ beta, float* __restrict__ scale,
    float* __restrict__ shift, int C, int HW) {
    int c = blockIdx.x;
    int tid = threadIdx.x;
    int N = 512 * HW;
    float s = 0.0f, s2 = 0.0f;
    for (int i = tid; i < N; i += 256) {
        int b = i / HW, hw = i - (i / HW) * HW;
        float v = a[(b * C + c) * HW + hw];
        s += v;
        s2 += v * v;
    }
    __shared__ float red0[256], red1[256];
    red0[tid] = s; red1[tid] = s2;
    __syncthreads();
    for (int off = 128; off > 0; off >>= 1) {
        if (tid < off) { red0[tid] += red0[tid + off]; red1[tid] += red1[tid + off]; }
        __syncthreads();
    }
    if (tid == 0) {
        float mean = red0[0] / (float)N;
        float var = red1[0] / (float)N - mean * mean;
        float rs = rsqrtf(var + 1e-5f);
        float scl = gamma[c] * rs;
        scale[c] = scl;
        shift[c] = beta[c] - mean * scl;
    }
}

// BN3 + avgpool(2x2) + FC(128->1) + sigmoid. One wave per batch element.
__global__ void head_ker(const float* __restrict__ a4, const float* __restrict__ scale,
                         const float* __restrict__ shift, const float* __restrict__ fcw,
                         const float* __restrict__ fcb, float* __restrict__ out) {
    int b = blockIdx.x;
    int lane = threadIdx.x;  // 64
    float acc = 0.0f;
#pragma unroll
    for (int j = 0; j < 2; ++j) {
        int o = lane + 64 * j;
        const float* p = a4 + (b * 128 + o) * 4;
        float sv = p[0] + p[1] + p[2] + p[3];
        float pooled = fmaf(sv * 0.25f, scale[o], shift[o]);
        acc = fmaf(pooled, fcw[o], acc);
    }
#pragma unroll
    for (int off = 32; off > 0; off >>= 1) acc += __shfl_down(acc, off);
    if (lane == 0) out[b] = 1.0f / (1.0f + expf(-(acc + fcb[0])));
}

extern "C" void kernel_launch(void* const* d_in, const int* in_sizes, int n_in,
                              void* d_out, int out_size, void* d_ws, size_t ws_size,
                              hipStream_t stream) {
    const float* x   = (const float*)d_in[0];
    const float* bw1 = (const float*)d_in[1];
    const float* sw1 = (const float*)d_in[2];
    const float* sc1 = (const float*)d_in[3];
    const float* bw2 = (const float*)d_in[4];
    const float* sw2 = (const float*)d_in[5];
    const float* sc2 = (const float*)d_in[6];
    const float* bw3 = (const float*)d_in[7];
    const float* sw3 = (const float*)d_in[8];
    const float* sc3 = (const float*)d_in[9];
    const float* bw4 = (const float*)d_in[10];
    const float* sw4 = (const float*)d_in[11];
    const float* sc4 = (const float*)d_in[12];
    const float* g1  = (const float*)d_in[13];
    const float* b1  = (const float*)d_in[14];
    const float* g2  = (const float*)d_in[15];
    const float* b2  = (const float*)d_in[16];
    const float* g3  = (const float*)d_in[17];
    const float* b3  = (const float*)d_in[18];
    const float* fcw = (const float*)d_in[19];
    const float* fcb = (const float*)d_in[20];

    float* ws = (float*)d_ws;
    float* a1 = ws;                    // 4194304 floats (dead after L2 -> P3)
    float* a2 = a1 + 4194304;          // 2097152 (dead after L3 expand -> P4)
    float* a3 = a2 + 2097152;          // 1048576
    float* a4 = a3 + 1048576;          // 262144
    float* bnsc1 = a4 + 262144;        // 64
    float* bnsh1 = bnsc1 + 64;
    float* bnsc2 = bnsh1 + 64;         // 128
    float* bnsh2 = bnsc2 + 128;
    float* bnsc3 = bnsh2 + 128;        // 128
    float* bnsh3 = bnsc3 + 128;        // +128
    unsigned short* wf1 = (unsigned short*)(bnsh3 + 128);  // 3*32*128   = 12288
    unsigned short* wf2 = wf1 + 12288;      // 32*64*128   = 262144
    unsigned short* wf3 = wf2 + 262144;     // 64*128*128  = 1048576
    unsigned short* wf4 = wf3 + 1048576;    // 128*128*128 = 2097152
    float* P3 = a1;                    // 4 * 8192*128 = 4194304 floats
    float* P4 = a2;                    // 8 * 2048*128 = 2097152 floats

    prep_wfrag<3, 32><<<48, 256, 0, stream>>>(bw1, sw1, sc1, wf1);
    prep_wfrag<32, 64><<<1024, 256, 0, stream>>>(bw2, sw2, sc2, wf2);
    prep_wfrag<64, 128><<<4096, 256, 0, stream>>>(bw3, sw3, sc3, wf3);
    prep_wfrag<128, 128><<<8192, 256, 0, stream>>>(bw4, sw4, sc4, wf4);

    // L1: (512,3,32,32) -> (512,32,16,16), M=131072, BM=256 (1 image)
    kan_conv_fused<3, 32, 16, 16, 4, 1, 4, 3, false, false, 0>
        <<<512, 256, 0, stream>>>(x, wf1, nullptr, nullptr, a1);
    // L2: -> (512,64,8,8), M=32768, BM=64 (1 image)
    kan_conv_fused<32, 64, 8, 8, 2, 2, 2, 32, false, false, 0>
        <<<512, 256, 0, stream>>>(a1, wf2, nullptr, nullptr, a2);
    bn_stats<<<64, 256, 0, stream>>>(a2, g1, b1, bnsc1, bnsh1, 64, 64);
    // L3: -> (512,128,4,4), M=8192, BM=64 (4 images), split-K 4x16ch, BN1 folded
    kan_conv_fused<64, 128, 4, 4, 1, 4, 4, 16, true, true, 1>
        <<<dim3(128, 4), 256, 0, stream>>>(a2, wf3, bnsc1, bnsh1, P3);
    reduce_split<4, 128, 4, 4><<<4096, 256, 0, stream>>>(P3, a3);
    bn_stats<<<128, 256, 0, stream>>>(a3, g2, b2, bnsc2, bnsh2, 128, 16);
    // L4: -> (512,128,2,2), M=2048, BM=32 (8 images), split-K 8x16ch, BN2 folded
    kan_conv_fused<128, 128, 2, 2, 1, 4, 2, 16, true, true, 0>
        <<<dim3(64, 8), 256, 0, stream>>>(a3, wf4, bnsc2, bnsh2, P4);
    reduce_split<8, 128, 2, 2><<<1024, 256, 0, stream>>>(P4, a4);
    bn_stats<<<128, 256, 0, stream>>>(a4, g3, b3, bnsc3, bnsh3, 128, 4);
    // Head: BN3 + pool + FC + sigmoid
    head_ker<<<512, 64, 0, stream>>>(a4, bnsc3, bnsh3, fcw, fcb, (float*)d_out);
}

// Round 4
// 146.715 us; speedup vs baseline: 8.5398x; 1.4299x over previous
//
#include <hip/hip_runtime.h>
#include <hip/hip_bf16.h>
#include <math.h>

#define DEVINL __device__ __forceinline__

typedef short short8 __attribute__((ext_vector_type(8)));
typedef float f32x4 __attribute__((ext_vector_type(4)));

DEVINL unsigned short f2bf(float f) {
    union { float f; unsigned int u; } c; c.f = f;
    unsigned int u = c.u;
    return (unsigned short)((u + 0x7fffu + ((u >> 16) & 1u)) >> 16);
}

DEVINL unsigned int packbf2(float a, float b) {
    union { __hip_bfloat162 h; unsigned int u; } c;
    c.h = __float22bfloat162_rn(make_float2(a, b));
    return c.u;  // a low 16, b high 16
}

DEVINL void gload_lds16(const unsigned int* g, unsigned int* l) {
    __builtin_amdgcn_global_load_lds((const __attribute__((address_space(1))) unsigned int*)g,
                                     (__attribute__((address_space(3))) unsigned int*)l, 16, 0, 0);
}

// Closed-form quadratic B-spline expansion, uniform extended grid
// (knots t_i=(i-2)*(2/3)-1): u=1.5x+3.5, j=floor(u), t=u-j.
// Frag = bf16x8 [relu(x), b0..b4, 0, 0].
DEVINL uint4 expand_frag(float v) {
    float relu = fmaxf(v, 0.f);
    float u = fmaf(v, 1.5f, 3.5f);
    float fj = floorf(u);
    int j = (int)fj;
    float t = u - fj;
    float omt = 1.f - t;
    float v2 = 0.5f * omt * omt;
    float v1 = fmaf(t, omt, 0.5f);
    float v0 = 0.5f * t * t;
    float b[5];
#pragma unroll
    for (int i = 0; i < 5; ++i)
        b[i] = (i == j) ? v0 : (i == j - 1) ? v1 : (i == j - 2) ? v2 : 0.f;
    uint4 r;
    r.x = packbf2(relu, b[0]);
    r.y = packbf2(b[1], b[2]);
    r.z = packbf2(b[3], b[4]);
    r.w = 0u;
    return r;
}

// Pack weights into MFMA B-fragment-linear layout, K padded to 8 slots/tap:
// wf[(((c*NT+nt)*4+ks)*64+lane)*8+j] = W[k][o], k=ks*32+(lane>>4)*8+j,
// o=nt*16+(lane&15); tap=k>>3, s=k&7: s==0->bw, 1..5->sw*sc, 6,7->0.
template <int CIN, int COUT>
__global__ __launch_bounds__(256) void prep_wfrag(const float* __restrict__ bw,
                                                  const float* __restrict__ sw,
                                                  const float* __restrict__ sc,
                                                  unsigned short* __restrict__ wf) {
    constexpr int F = CIN * 16;
    constexpr int NT = COUT / 16;
    int idx = blockIdx.x * 256 + threadIdx.x;
    if (idx >= CIN * COUT * 128) return;
    int j = idx & 7;
    int lane = (idx >> 3) & 63;
    int t = idx >> 9;
    int ks = t & 3;
    int t2 = t >> 2;
    int nt = t2 % NT;
    int c = t2 / NT;
    int k = ks * 32 + ((lane >> 4) << 3) + j;
    int tap = k >> 3, s = k & 7;
    int f = c * 16 + tap;
    int o = nt * 16 + (lane & 15);
    float v = 0.f;
    if (s == 0) v = bw[o * F + f];
    else if (s <= 5) v = sw[(o * F + f) * 5 + (s - 1)] * sc[o * F + f];
    wf[idx] = f2bf(v);
}

// Fused KAN conv: per phase stage UB channels' B frags (global_load_lds) +
// expand UB channels' input tiles into LDS -> one barrier -> UB*4 MFMA k-steps
// -> barrier. Invalid taps read slot 0 = expansion of v=0 (not BN'd).
template <int CIN, int COUT, int HOUT, int WOUT, int WM, int WN, int MT, int CPS,
          int UB, bool HASBN, bool SPLITOUT, int RPAD>
__global__ __launch_bounds__(256) void kan_conv_fused(
    const float* __restrict__ in, const unsigned short* __restrict__ wf,
    const float* __restrict__ bnscale, const float* __restrict__ bnshift,
    float* __restrict__ out) {
    constexpr int HIN = HOUT * 2, WIN = WOUT * 2, W2 = WOUT;
    constexpr int NT = COUT / 16;
    constexpr int NTW = NT / WN;
    constexpr int BM = WM * MT * 16;
    constexpr int IMG_POS = HOUT * WOUT;
    constexpr int NIMG = BM / IMG_POS;
    constexpr int RS = WIN + RPAD;
    constexpr int IMG_STRIDE = HIN * RS + 1;
    constexpr int ASLOTS = NIMG * IMG_STRIDE + 1;  // slot 0 = pad frag
    constexpr int M_TOT = 512 * IMG_POS;
    constexpr int EV = NIMG * HIN * WIN;
    constexpr int EITER = (EV + 255) / 256;
    static_assert(WM * WN == 4, "4 waves");
    static_assert(CPS % UB == 0, "UB divides CPS");

    __shared__ uint4 A_e[UB][ASLOTS];
    __shared__ uint4 B_l[UB][COUT * 16];

    const int tid = threadIdx.x;
    const int lane = tid & 63;
    const int w = tid >> 6;
    const int wm = w % WM;
    const int wn = w / WM;
    const int g = lane >> 4;        // kw
    const int r16 = lane & 15;
    const int m0 = blockIdx.x * BM;
    const int b0 = m0 / IMG_POS;
    const int c0 = SPLITOUT ? blockIdx.y * CPS : 0;

    // Per-mt fragment geometry (channel-invariant).
    int aoff[MT];
    int vmask = 0;
#pragma unroll
    for (int mt = 0; mt < MT; ++mt) {
        int p = (wm * MT + mt) * 16 + r16;
        int m = m0 + p;
        int ow = m % WOUT;
        int oh = (m / WOUT) % HOUT;
        int bl = p / IMG_POS;
        int iw = 2 * ow - 1 + g;
        bool iv = (iw >= 0) && (iw < WIN);
        aoff[mt] = 1 + bl * IMG_STRIDE + (2 * oh) * RS + (iw & 1) * W2 + (iw >> 1);
#pragma unroll
        for (int ks = 0; ks < 4; ++ks) {
            bool vv = iv && !(oh == 0 && ks == 0) && !(oh == HOUT - 1 && ks == 3);
            vmask |= (vv ? 1 : 0) << (mt * 4 + ks);
        }
    }

    if (tid < UB) A_e[tid][0] = expand_frag(0.f);  // pad slots (covered by 1st barrier)

    f32x4 acc[MT][NTW];
#pragma unroll
    for (int mt = 0; mt < MT; ++mt)
#pragma unroll
        for (int n = 0; n < NTW; ++n) acc[mt][n] = f32x4{0.f, 0.f, 0.f, 0.f};

    for (int cc = 0; cc < CPS; cc += UB) {
        // (1) issue all B staging for the UB channels
#pragma unroll
        for (int u = 0; u < UB; ++u) {
            const int ch = c0 + cc + u;
            const unsigned int* bsrc = (const unsigned int*)(wf + (size_t)ch * (COUT * 128));
            unsigned int* bdst = (unsigned int*)&B_l[u][0];
#pragma unroll
            for (int r2 = 0; r2 < NT; ++r2)
                gload_lds16(bsrc + ((r2 << 8) + tid) * 4, bdst + ((r2 << 8) + tid) * 4);
        }
        // (2) expand UB channels' tiles (once per element)
#pragma unroll
        for (int u = 0; u < UB; ++u) {
            const int ch = c0 + cc + u;
            float bsc = 1.f, bsh = 0.f;
            if (HASBN) { bsc = bnscale[ch]; bsh = bnshift[ch]; }
#pragma unroll
            for (int ii = 0; ii < EITER; ++ii) {
                int e = tid + ii * 256;
                if (e < EV) {
                    int bl = e / (HIN * WIN);
                    int r = e - bl * (HIN * WIN);
                    int ih = r / WIN;
                    int iw = r - ih * WIN;
                    float v = in[(((size_t)(b0 + bl) * CIN + ch) * HIN + ih) * WIN + iw];
                    if (HASBN) v = fmaf(v, bsc, bsh);
                    A_e[u][1 + bl * IMG_STRIDE + ih * RS + (iw & 1) * W2 + (iw >> 1)] = expand_frag(v);
                }
            }
        }
        __syncthreads();  // drains gload_lds (vmcnt) + ds_writes (lgkm)
        // (3) MFMA: UB x 4 k-steps x MT x NTW
#pragma unroll
        for (int u = 0; u < UB; ++u) {
#pragma unroll
            for (int ks = 0; ks < 4; ++ks) {
                short8 bf[NTW];
#pragma unroll
                for (int n = 0; n < NTW; ++n)
                    bf[n] = *(const short8*)&B_l[u][(((wn * NTW + n) * 4 + ks) << 6) + lane];
#pragma unroll
                for (int mt = 0; mt < MT; ++mt) {
                    int slot = ((vmask >> (mt * 4 + ks)) & 1) ? (aoff[mt] + (ks - 1) * RS) : 0;
                    short8 af = *(const short8*)&A_e[u][slot];
#pragma unroll
                    for (int n = 0; n < NTW; ++n)
                        acc[mt][n] = __builtin_amdgcn_mfma_f32_16x16x32_bf16(af, bf[n], acc[mt][n], 0, 0, 0);
                }
            }
        }
        __syncthreads();  // buffers reused next phase
    }

    // Epilogue. D mapping: col=lane&15, row=(lane>>4)*4+reg [m89].
    const int colo = lane & 15;
    const int row4 = (lane >> 4) * 4;
#pragma unroll
    for (int mt = 0; mt < MT; ++mt) {
#pragma unroll
        for (int n = 0; n < NTW; ++n) {
            int o = (wn * NTW + n) * 16 + colo;
#pragma unroll
            for (int rr = 0; rr < 4; ++rr) {
                int p = (wm * MT + mt) * 16 + row4 + rr;
                int m = m0 + p;
                if (SPLITOUT) {
                    out[((size_t)blockIdx.y * M_TOT + m) * COUT + o] = acc[mt][n][rr];
                } else {
                    int ow = m % WOUT;
                    int t = m / WOUT;
                    int oh = t % HOUT;
                    int b = t / HOUT;
                    out[((b * COUT + o) * HOUT + oh) * WOUT + ow] = acc[mt][n][rr];
                }
            }
        }
    }
}

// Deterministic fixed-order reduction of split-K partials -> NCHW (f4 reads).
template <int NS, int COUT, int HOUT, int WOUT>
__global__ __launch_bounds__(256) void reduce_split(const float* __restrict__ P,
                                                    float* __restrict__ out) {
    constexpr int M = 512 * HOUT * WOUT;
    int idx4 = blockIdx.x * 256 + threadIdx.x;
    if (idx4 >= M * COUT / 4) return;
    f32x4 s = {0.f, 0.f, 0.f, 0.f};
#pragma unroll
    for (int i = 0; i < NS; ++i) {
        f32x4 v = *(const f32x4*)&P[(size_t)i * M * COUT + idx4 * 4];
        s += v;
    }
    int o0 = (idx4 * 4) % COUT;   // COUT%4==0 -> 4 consecutive o, same m
    int m = (idx4 * 4) / COUT;
    int ow = m % WOUT;
    int t = m / WOUT;
    int oh = t % HOUT;
    int b = t / HOUT;
#pragma unroll
    for (int q = 0; q < 4; ++q)
        out[((b * COUT + o0 + q) * HOUT + oh) * WOUT + ow] = s[q];
}

// Two-stage deterministic BN stats. Stage 1: grid C*S blocks, block (c,s)
// sums a over its batch slice -> partials. Stage 2: one block, thread c
// reduces S partials in fixed order -> fused scale/shift.
template <int C, int HW, int S>
__global__ __launch_bounds__(256) void bn_partial(const float* __restrict__ a,
                                                  float* __restrict__ part) {
    constexpr int BS = 512 / S;
    constexpr int NE = BS * HW;
    int c = blockIdx.x / S, s = blockIdx.x % S;
    int tid = threadIdx.x;
    float sm = 0.f, s2 = 0.f;
    for (int e = tid; e < NE; e += 256) {
        int b = s * BS + e / HW;
        int hw = e % HW;
        float v = a[((size_t)b * C + c) * HW + hw];
        sm += v;
        s2 += v * v;
    }
    __shared__ float r0[256], r1[256];
    r0[tid] = sm; r1[tid] = s2;
    __syncthreads();
    for (int off = 128; off > 0; off >>= 1) {
        if (tid < off) { r0[tid] += r0[tid + off]; r1[tid] += r1[tid + off]; }
        __syncthreads();
    }
    if (tid == 0) {
        part[(c * S + s) * 2] = r0[0];
        part[(c * S + s) * 2 + 1] = r1[0];
    }
}

template <int C, int HW, int S>
__global__ void bn_finish(const float* __restrict__ part, const float* __restrict__ gamma,
                          const float* __restrict__ beta, float* __restrict__ scale,
                          float* __restrict__ shift) {
    int c = threadIdx.x;
    if (c >= C) return;
    float sm = 0.f, s2 = 0.f;
#pragma unroll 4
    for (int s = 0; s < S; ++s) {
        sm += part[(c * S + s) * 2];
        s2 += part[(c * S + s) * 2 + 1];
    }
    const float invN = 1.f / (float)(512 * HW);
    float mean = sm * invN;
    float var = s2 * invN - mean * mean;
    float rs = rsqrtf(var + 1e-5f);
    float scl = gamma[c] * rs;
    scale[c] = scl;
    shift[c] = beta[c] - mean * scl;
}

// BN3 + avgpool(2x2) + FC(128->1) + sigmoid. One wave per batch element.
__global__ void head_ker(const float* __restrict__ a4, const float* __restrict__ scale,
                         const float* __restrict__ shift, const float* __restrict__ fcw,
                         const float* __restrict__ fcb, float* __restrict__ out) {
    int b = blockIdx.x;
    int lane = threadIdx.x;  // 64
    float acc = 0.0f;
#pragma unroll
    for (int j = 0; j < 2; ++j) {
        int o = lane + 64 * j;
        const float* p = a4 + (b * 128 + o) * 4;
        float sv = p[0] + p[1] + p[2] + p[3];
        float pooled = fmaf(sv * 0.25f, scale[o], shift[o]);
        acc = fmaf(pooled, fcw[o], acc);
    }
#pragma unroll
    for (int off = 32; off > 0; off >>= 1) acc += __shfl_down(acc, off);
    if (lane == 0) out[b] = 1.0f / (1.0f + expf(-(acc + fcb[0])));
}

extern "C" void kernel_launch(void* const* d_in, const int* in_sizes, int n_in,
                              void* d_out, int out_size, void* d_ws, size_t ws_size,
                              hipStream_t stream) {
    const float* x   = (const float*)d_in[0];
    const float* bw1 = (const float*)d_in[1];
    const float* sw1 = (const float*)d_in[2];
    const float* sc1 = (const float*)d_in[3];
    const float* bw2 = (const float*)d_in[4];
    const float* sw2 = (const float*)d_in[5];
    const float* sc2 = (const float*)d_in[6];
    const float* bw3 = (const float*)d_in[7];
    const float* sw3 = (const float*)d_in[8];
    const float* sc3 = (const float*)d_in[9];
    const float* bw4 = (const float*)d_in[10];
    const float* sw4 = (const float*)d_in[11];
    const float* sc4 = (const float*)d_in[12];
    const float* g1  = (const float*)d_in[13];
    const float* b1  = (const float*)d_in[14];
    const float* g2  = (const float*)d_in[15];
    const float* b2  = (const float*)d_in[16];
    const float* g3  = (const float*)d_in[17];
    const float* b3  = (const float*)d_in[18];
    const float* fcw = (const float*)d_in[19];
    const float* fcb = (const float*)d_in[20];

    float* ws = (float*)d_ws;
    float* a1 = ws;                    // 4194304 floats (dead after L2 -> P3)
    float* a2 = a1 + 4194304;          // 2097152 (dead after L3 expand -> P4)
    float* a3 = a2 + 2097152;          // 1048576
    float* a4 = a3 + 1048576;          // 262144
    float* bnsc1 = a4 + 262144;        // 64
    float* bnsh1 = bnsc1 + 64;
    float* bnsc2 = bnsh1 + 64;         // 128
    float* bnsh2 = bnsc2 + 128;
    float* bnsc3 = bnsh2 + 128;        // 128
    float* bnsh3 = bnsc3 + 128;        // +128
    unsigned short* wf1 = (unsigned short*)(bnsh3 + 128);  // 3*32*128   = 12288
    unsigned short* wf2 = wf1 + 12288;      // 32*64*128   = 262144
    unsigned short* wf3 = wf2 + 262144;     // 64*128*128  = 1048576
    unsigned short* wf4 = wf3 + 1048576;    // 128*128*128 = 2097152
    float* part1 = (float*)(wf4 + 2097152); // 64*16*2  = 2048
    float* part2 = part1 + 2048;            // 128*16*2 = 4096
    float* part3 = part2 + 4096;            // 128*8*2  = 2048
    float* P3 = a1;                    // 4 * 8192*128 = 4194304 floats
    float* P4 = a2;                    // 8 * 2048*128 = 2097152 floats

    prep_wfrag<3, 32><<<48, 256, 0, stream>>>(bw1, sw1, sc1, wf1);
    prep_wfrag<32, 64><<<1024, 256, 0, stream>>>(bw2, sw2, sc2, wf2);
    prep_wfrag<64, 128><<<4096, 256, 0, stream>>>(bw3, sw3, sc3, wf3);
    prep_wfrag<128, 128><<<8192, 256, 0, stream>>>(bw4, sw4, sc4, wf4);

    // L1: (512,3,32,32) -> (512,32,16,16), BM=256, single phase (UB=3)
    kan_conv_fused<3, 32, 16, 16, 4, 1, 4, 3, 3, false, false, 0>
        <<<512, 256, 0, stream>>>(x, wf1, nullptr, nullptr, a1);
    // L2: -> (512,64,8,8), BM=64, UB=2 (16 phases)
    kan_conv_fused<32, 64, 8, 8, 2, 2, 2, 32, 2, false, false, 0>
        <<<512, 256, 0, stream>>>(a1, wf2, nullptr, nullptr, a2);
    bn_partial<64, 64, 16><<<1024, 256, 0, stream>>>(a2, part1);
    bn_finish<64, 64, 16><<<1, 64, 0, stream>>>(part1, g1, b1, bnsc1, bnsh1);
    // L3: -> (512,128,4,4), BM=64, split-K 4x16ch, UB=2, BN1 folded
    kan_conv_fused<64, 128, 4, 4, 1, 4, 4, 16, 2, true, true, 1>
        <<<dim3(128, 4), 256, 0, stream>>>(a2, wf3, bnsc1, bnsh1, P3);
    reduce_split<4, 128, 4, 4><<<1024, 256, 0, stream>>>(P3, a3);
    bn_partial<128, 16, 16><<<2048, 256, 0, stream>>>(a3, part2);
    bn_finish<128, 16, 16><<<1, 128, 0, stream>>>(part2, g2, b2, bnsc2, bnsh2);
    // L4: -> (512,128,2,2), BM=32, split-K 8x16ch, UB=2, BN2 folded
    kan_conv_fused<128, 128, 2, 2, 1, 4, 2, 16, 2, true, true, 0>
        <<<dim3(64, 8), 256, 0, stream>>>(a3, wf4, bnsc2, bnsh2, P4);
    reduce_split<8, 128, 2, 2><<<256, 256, 0, stream>>>(P4, a4);
    bn_partial<128, 4, 8><<<1024, 256, 0, stream>>>(a4, part3);
    bn_finish<128, 4, 8><<<1, 128, 0, stream>>>(part3, g3, b3, bnsc3, bnsh3);
    // Head: BN3 + pool + FC + sigmoid
    head_ker<<<512, 64, 0, stream>>>(a4, bnsc3, bnsh3, fcw, fcb, (float*)d_out);
}